// Round 6
// baseline (2054.370 us; speedup 1.0000x reference)
//
#include <hip/hip_runtime.h>

#define BB 256
#define TT 1024
#define KK 64
#define CH 8          // staged chunk length (steps)
#define NCH (TT/CH)   // 128 chunks

// ---------------------------------------------------------------------------
// Grid: 512 blocks x 192 threads (3 waves).
//  blocks [0,256):   forward logsumexp chains.
//  blocks [256,512): Viterbi chains (+ in-LDS backtrace epilogue).
// Waves 0-1: recurrence, i-split by 2 (wave w: states j in [32w,32w+32),
//   lane ig=l>>5 covers i in [32ig,32ig+32); combine via shfl_xor(32)).
//   Consumer waves issue NO global memory ops in the 1023-step loop, so the
//   compiler's s_waitcnt before s_barrier has no vmcnt to drain (R4's 900cy
//   per-step stall).
// Wave 2: stager — double-buffers 8-step emission chunks global->LDS and
//   pre-stages the mask row. Its vmcnt drains overlap the consumers' 8-step
//   compute slack. Role-0 stager computes the path score after the loop.
// ---------------------------------------------------------------------------
__global__ __launch_bounds__(192) void crf_mega_kernel(
    const float* __restrict__ em, const int* __restrict__ mask,
    const float* __restrict__ trans, const int* __restrict__ tags,
    float* __restrict__ out_dec, float* ll_sum, int* match, int* maskSum) {

  __shared__ __align__(16) float sd[2][KK];        // s (fwd) or delta (vit)
  __shared__ __align__(16) float ebuf[2][CH * KK]; // staged emissions (4 KB)
  __shared__ unsigned char mrow[TT];               // mask row
  __shared__ unsigned char bpl[TT][KK];            // backpointers (64 KB)
  __shared__ unsigned char segm[32][KK];           // composed 32-step maps
  __shared__ unsigned char bs[40];                 // boundary states
  __shared__ int redm[32];

  const int role = (blockIdx.x >= BB) ? 1 : 0;
  const int b = blockIdx.x & (BB - 1);
  const int tid = threadIdx.x;
  const int wv = tid >> 6;     // 0,1 = recurrence; 2 = stager
  const int l = tid & 63;
  const int ig = l >> 5;
  const int jl = l & 31;
  const int j = (wv << 5) + jl;    // consumers only (wv<2)
  const int ibase = ig << 5;

  const float* emb = em + (size_t)b * TT * KK;
  const int* mb = mask + (size_t)b * TT;
  const int* tgb = tags + (size_t)b * TT;

  float TRW[32];   // E=exp(trans) slice (fwd) or trans slice (vit)
  if (wv < 2) {
    if (role == 0) {
#pragma unroll
      for (int r = 0; r < 32; ++r) TRW[r] = __expf(trans[(ibase + r) * KK + j]);
    } else {
#pragma unroll
      for (int r = 0; r < 32; ++r) TRW[r] = trans[(ibase + r) * KK + j];
    }
  } else {
    // stager prologue: mask row + chunk 0
    for (int t = l; t < TT; t += 64)
      mrow[t] = (unsigned char)(mb[t] ? 1 : 0);
    const float4* g4 = reinterpret_cast<const float4*>(emb);
    float4 v0 = g4[l], v1 = g4[l + 64];
    float4* eb = reinterpret_cast<float4*>(&ebuf[0][0]);
    eb[l] = v0; eb[l + 64] = v1;
  }
  __syncthreads();  // B0: chunk0 + mrow visible

  float offset = 0.f;
  if (wv < 2) {
    if (role == 0) {  // fwd init: m0 = max(e0); s = exp(e0 - m0) -> sd[1]
      const float4* e0v = reinterpret_cast<const float4*>(&ebuf[0][ibase]);
      float4 x0 = e0v[0], x1 = e0v[1], x2 = e0v[2], x3 = e0v[3];
      float4 x4 = e0v[4], x5 = e0v[5], x6 = e0v[6], x7 = e0v[7];
      float g01 = fmaxf(fmaxf(x0.x, x0.y), fmaxf(x0.z, x0.w));
      float g11 = fmaxf(fmaxf(x1.x, x1.y), fmaxf(x1.z, x1.w));
      float g21 = fmaxf(fmaxf(x2.x, x2.y), fmaxf(x2.z, x2.w));
      float g31 = fmaxf(fmaxf(x3.x, x3.y), fmaxf(x3.z, x3.w));
      float g41 = fmaxf(fmaxf(x4.x, x4.y), fmaxf(x4.z, x4.w));
      float g51 = fmaxf(fmaxf(x5.x, x5.y), fmaxf(x5.z, x5.w));
      float g61 = fmaxf(fmaxf(x6.x, x6.y), fmaxf(x6.z, x6.w));
      float g71 = fmaxf(fmaxf(x7.x, x7.y), fmaxf(x7.z, x7.w));
      float gm = fmaxf(fmaxf(fmaxf(g01, g11), fmaxf(g21, g31)),
                       fmaxf(fmaxf(g41, g51), fmaxf(g61, g71)));
      gm = fmaxf(gm, __shfl_xor(gm, 32));
      offset = gm;
      if (ig == 0) sd[1][j] = __expf(ebuf[0][j] - gm);
    } else {          // vit init: delta0 = e0
      if (ig == 0) sd[1][j] = ebuf[0][j];
    }
  }
  __syncthreads();  // B1: sd init visible

  if (wv < 2) {
    if (role == 0) {
      // ======================= FORWARD consumers =======================
      for (int t = 1; t < TT; ++t) {
        int p = t & 1, pn = p ^ 1;
        const float4* sv = reinterpret_cast<const float4*>(&sd[p][ibase]);
        float4 a0 = sv[0], a1 = sv[1], a2 = sv[2], a3 = sv[3];
        float4 a4 = sv[4], a5 = sv[5], a6 = sv[6], a7 = sv[7];
        float sown = sd[p][j];
        float q0 = a0.x*TRW[0]  + a0.y*TRW[1]  + a0.z*TRW[2]  + a0.w*TRW[3];
        float q1 = a1.x*TRW[4]  + a1.y*TRW[5]  + a1.z*TRW[6]  + a1.w*TRW[7];
        float q2 = a2.x*TRW[8]  + a2.y*TRW[9]  + a2.z*TRW[10] + a2.w*TRW[11];
        float q3 = a3.x*TRW[12] + a3.y*TRW[13] + a3.z*TRW[14] + a3.w*TRW[15];
        float q4 = a4.x*TRW[16] + a4.y*TRW[17] + a4.z*TRW[18] + a4.w*TRW[19];
        float q5 = a5.x*TRW[20] + a5.y*TRW[21] + a5.z*TRW[22] + a5.w*TRW[23];
        float q6 = a6.x*TRW[24] + a6.y*TRW[25] + a6.z*TRW[26] + a6.w*TRW[27];
        float q7 = a7.x*TRW[28] + a7.y*TRW[29] + a7.z*TRW[30] + a7.w*TRW[31];
        float q = ((q0 + q1) + (q2 + q3)) + ((q4 + q5) + (q6 + q7));
        q += __shfl_xor(q, 32);
        float e = ebuf[(t >> 3) & 1][((t & 7) << 6) + j];
        q *= __expf(e);
        q = mrow[t] ? q : sown;
        if ((t & 7) == 0) {  // renorm from pre-update s (identical all lanes)
          float g01 = fmaxf(fmaxf(a0.x, a0.y), fmaxf(a0.z, a0.w));
          float g11 = fmaxf(fmaxf(a1.x, a1.y), fmaxf(a1.z, a1.w));
          float g21 = fmaxf(fmaxf(a2.x, a2.y), fmaxf(a2.z, a2.w));
          float g31 = fmaxf(fmaxf(a3.x, a3.y), fmaxf(a3.z, a3.w));
          float g41 = fmaxf(fmaxf(a4.x, a4.y), fmaxf(a4.z, a4.w));
          float g51 = fmaxf(fmaxf(a5.x, a5.y), fmaxf(a5.z, a5.w));
          float g61 = fmaxf(fmaxf(a6.x, a6.y), fmaxf(a6.z, a6.w));
          float g71 = fmaxf(fmaxf(a7.x, a7.y), fmaxf(a7.z, a7.w));
          float gm = fmaxf(fmaxf(fmaxf(g01, g11), fmaxf(g21, g31)),
                           fmaxf(fmaxf(g41, g51), fmaxf(g61, g71)));
          gm = fmaxf(gm, __shfl_xor(gm, 32));
          q *= __builtin_amdgcn_rcpf(gm);
          offset += __logf(gm);
        }
        if (ig == 0) sd[pn][j] = q;
        __syncthreads();
      }
      // final: sum s (slice + cross-half), lane (wv0,l0) commits
      const float4* sv = reinterpret_cast<const float4*>(&sd[0][ibase]);
      float fs = 0.f;
#pragma unroll
      for (int k = 0; k < 8; ++k) {
        float4 x = sv[k];
        fs += (x.x + x.y) + (x.z + x.w);
      }
      fs += __shfl_xor(fs, 32);
      if (wv == 0 && l == 0) atomicAdd(ll_sum, -(offset + __logf(fs)));
    } else {
      // ======================= VITERBI consumers =======================
      for (int t = 1; t < TT; ++t) {
        int p = t & 1, pn = p ^ 1;
        const float4* dv = reinterpret_cast<const float4*>(&sd[p][ibase]);
        float v[32];
#pragma unroll
        for (int k = 0; k < 8; ++k) {
          float4 x = dv[k];
          v[4*k]   = x.x + TRW[4*k];
          v[4*k+1] = x.y + TRW[4*k+1];
          v[4*k+2] = x.z + TRW[4*k+2];
          v[4*k+3] = x.w + TRW[4*k+3];
        }
        float down = sd[p][j];
        // balanced tournament, ties -> lower index (numpy first-occurrence)
        float tv[16]; int ti[16];
#pragma unroll
        for (int k = 0; k < 16; ++k) {
          bool tk = v[2*k+1] > v[2*k];
          tv[k] = tk ? v[2*k+1] : v[2*k];
          ti[k] = tk ? 2*k+1 : 2*k;
        }
#pragma unroll
        for (int k = 0; k < 8; ++k) {
          bool tk = tv[k+8] > tv[k];
          tv[k] = tk ? tv[k+8] : tv[k];
          ti[k] = tk ? ti[k+8] : ti[k];
        }
#pragma unroll
        for (int k = 0; k < 4; ++k) {
          bool tk = tv[k+4] > tv[k];
          tv[k] = tk ? tv[k+4] : tv[k];
          ti[k] = tk ? ti[k+4] : ti[k];
        }
#pragma unroll
        for (int k = 0; k < 2; ++k) {
          bool tk = tv[k+2] > tv[k];
          tv[k] = tk ? tv[k+2] : tv[k];
          ti[k] = tk ? ti[k+2] : ti[k];
        }
        bool tk0 = tv[1] > tv[0];
        float best = tk0 ? tv[1] : tv[0];
        int bidx = ibase + (tk0 ? ti[1] : ti[0]);
        float ob = __shfl_xor(best, 32);
        int oi = __shfl_xor(bidx, 32);
        bool take = (ob > best) || ((ob == best) && (oi < bidx));
        best = take ? ob : best;
        bidx = take ? oi : bidx;
        float e = ebuf[(t >> 3) & 1][((t & 7) << 6) + j];
        int m = mrow[t];
        float nd = m ? (best + e) : down;
        int bp = m ? bidx : j;
        if (ig == 0) {
          sd[pn][j] = nd;
          bpl[t][j] = (unsigned char)bp;
        }
        __syncthreads();
      }
    }
  } else {
    // ============================ STAGER ============================
    float4 stg0 = {0,0,0,0}, stg1 = {0,0,0,0};
    for (int t = 1; t < TT; ++t) {
      int k = t & 7, c = t >> 3;
      if (k == 1 && c + 1 < NCH) {
        const float4* g4 =
            reinterpret_cast<const float4*>(emb + (size_t)(c + 1) * CH * KK);
        stg0 = g4[l];
        stg1 = g4[l + 64];
      }
      if (k == 6 && c + 1 < NCH) {
        float4* eb = reinterpret_cast<float4*>(&ebuf[(c + 1) & 1][0]);
        eb[l] = stg0;
        eb[l + 64] = stg1;
      }
      __syncthreads();
    }
  }

  if (role == 1) {
    // ---- epilogue (all 3 waves; barriers uniform) ----
    __syncthreads();  // bpl/sd/mrow complete
    if (tid < 128) {  // compose 32-step maps: 2048 chains, 16/thread
      int j0 = tid & 63;
      int sh = tid >> 6;  // 0..1 ; chains s = sh + 2*kk
      int xs[16], tEnd[16], tStart[16];
#pragma unroll
      for (int kk = 0; kk < 16; ++kk) {
        int s = sh + 2 * kk;
        xs[kk] = j0;
        tStart[kk] = 32 * s + 1;
        tEnd[kk] = (s == 31) ? (TT - 1) : (32 * s + 32);
      }
      for (int q = 0; q < 32; ++q) {
#pragma unroll
        for (int kk = 0; kk < 16; ++kk) {
          int t = tEnd[kk] - q;
          if (t >= tStart[kk]) xs[kk] = bpl[t][xs[kk]];
        }
      }
#pragma unroll
      for (int kk = 0; kk < 16; ++kk)
        segm[sh + 2 * kk][j0] = (unsigned char)xs[kk];
    }
    __syncthreads();

    if (tid == 0) {  // last_tag argmax (delta in sd[0]) + boundary walk
      float bd = sd[0][0];
      int lt = 0;
      for (int i = 1; i < KK; ++i) {
        float v2 = sd[0][i];
        if (v2 > bd) { bd = v2; lt = i; }
      }
      bs[32] = (unsigned char)lt;
      for (int s = 31; s >= 0; --s) bs[s] = segm[s][bs[s + 1]];
    }
    __syncthreads();

    if (tid < 32) {  // per-segment backtrace
      int s = tid;
      int x = bs[s + 1];
      int cnt = 0;
      int tEnd = (s == 31) ? (TT - 1) : (32 * s + 32);
      if (s == 31) {
        int m = mrow[TT - 1];
        out_dec[(size_t)b * TT + TT - 1] = (float)(m ? x : 0);
        cnt += (m && x == tgb[TT - 1]);
      }
      for (int t = tEnd; t >= 32 * s + 1; --t) {
        x = bpl[t][x];
        int m2 = mrow[t - 1];
        out_dec[(size_t)b * TT + t - 1] = (float)(m2 ? x : 0);
        cnt += (m2 && x == tgb[t - 1]);
      }
      redm[s] = cnt;
    }
    __syncthreads();
    if (tid == 0) {
      int c = 0;
      for (int s = 0; s < 32; ++s) c += redm[s];
      atomicAdd(match, c);
    }
  } else if (wv == 2) {
    // ---- role-0 stager tail: path score (no barriers) ----
    float acc = 0.f;
    int cnt = 0;
    for (int t = l; t < TT; t += 64) {
      if (mb[t]) {
        int tg = tgb[t];
        acc += emb[(size_t)t * KK + tg];
        cnt += 1;
        if (t >= 1) acc += trans[tgb[t - 1] * KK + tg];
      }
    }
#pragma unroll
    for (int off = 1; off <= 32; off <<= 1) {
      acc += __shfl_xor(acc, off);
      cnt += __shfl_xor(cnt, off);
    }
    if (l == 0) { atomicAdd(ll_sum, acc); atomicAdd(maskSum, cnt); }
  }
}

__global__ void finalize_kernel(const float* ll_sum, const int* match,
                                const int* maskSum, float* d_out) {
  d_out[0] = -(*ll_sum) / (float)BB;
  d_out[1 + BB * TT] = (float)(*match) / (float)(*maskSum);
}

extern "C" void kernel_launch(void* const* d_in, const int* in_sizes, int n_in,
                              void* d_out, int out_size, void* d_ws, size_t ws_size,
                              hipStream_t stream) {
  const float* em = (const float*)d_in[0];
  const int* tags = (const int*)d_in[1];
  const int* mask = (const int*)d_in[2];       // bool -> int32 on device
  const float* trans = (const float*)d_in[3];
  float* out = (float*)d_out;

  float* ll_sum = (float*)d_ws;
  int* match = (int*)((char*)d_ws + 4);
  int* maskSum = (int*)((char*)d_ws + 8);

  hipMemsetAsync(d_ws, 0, 12, stream);
  crf_mega_kernel<<<2 * BB, 192, 0, stream>>>(em, mask, trans, tags, out + 1,
                                              ll_sum, match, maskSum);
  finalize_kernel<<<1, 1, 0, stream>>>(ll_sum, match, maskSum, out);
}

// Round 7
// 1017.973 us; speedup vs baseline: 2.0181x; 2.0181x over previous
//
#include <hip/hip_runtime.h>

#define BB 256
#define TT 1024
#define KK 64

// ---------------------------------------------------------------------------
// Grid: 512 blocks x 128 threads, __launch_bounds__(128,1) -> 1 wave/SIMD,
// ~512 VGPR budget/wave so the 16 ds_read_b128 per step stay in flight
// (R5's serialization fix). ZERO __syncthreads in this kernel.
//  blocks [0,256):   wave0 = forward logsumexp chain; wave1 = path score.
//  blocks [256,512): wave0 = Viterbi chain + in-wave epilogue; wave1 exits.
// ---------------------------------------------------------------------------
__global__ __launch_bounds__(128, 1) void crf_mega_kernel(
    const float* __restrict__ em, const int* __restrict__ mask,
    const float* __restrict__ trans, const int* __restrict__ tags,
    float* __restrict__ out_dec, float* ll_sum, int* match, int* maskSum) {

  __shared__ __align__(16) float sd[2][KK];  // s (fwd) or delta (vit)
  __shared__ unsigned char bpl[TT][KK];      // backpointers (64 KB)
  __shared__ unsigned char mrow[TT];         // mask row
  __shared__ unsigned char segm[32][KK];     // composed 32-step maps
  __shared__ unsigned char bs[40];           // boundary states

  const int role = (blockIdx.x >= BB) ? 1 : 0;
  const int b = blockIdx.x & (BB - 1);
  const int tid = threadIdx.x;
  const int wv = tid >> 6;
  const int l = tid & 63;

  const float* emb = em + (size_t)b * TT * KK;
  const int* mb = mask + (size_t)b * TT;
  const int* tgb = tags + (size_t)b * TT;

  if (role == 0 && wv == 1) {
    // ---------------- path score (independent wave) ----------------
    float acc = 0.f;
    int cnt = 0;
    for (int t = l; t < TT; t += 64) {
      if (mb[t]) {
        int tg = tgb[t];
        acc += emb[(size_t)t * KK + tg];
        cnt += 1;
        if (t >= 1) acc += trans[tgb[t - 1] * KK + tg];
      }
    }
#pragma unroll
    for (int off = 1; off <= 32; off <<= 1) {
      acc += __shfl_xor(acc, off);
      cnt += __shfl_xor(cnt, off);
    }
    if (l == 0) { atomicAdd(ll_sum, acc); atomicAdd(maskSum, cnt); }
    return;
  }
  if (role == 1 && wv == 1) return;

  // =============== wave0: sequential chain (lane = state j) ===============
  const int j = l;
  for (int t = l; t < TT; t += 64) mrow[t] = (unsigned char)(mb[t] ? 1 : 0);

  if (role == 0) {
    // =========================== FORWARD ===========================
    float E[KK];
#pragma unroll
    for (int r = 0; r < KK; ++r) E[r] = __expf(trans[r * KK + j]);

    // init: raw e0 -> sd[0]; m0 = max; s = exp(e0-m0) -> sd[1]
    float e0 = emb[j];
    sd[0][j] = e0;
    float m0;
    {
      const float4* rv = reinterpret_cast<const float4*>(&sd[0][0]);
      float gm = -3.4e38f;
#pragma unroll
      for (int k = 0; k < 16; ++k) {
        float4 x = rv[k];
        gm = fmaxf(gm, fmaxf(fmaxf(x.x, x.y), fmaxf(x.z, x.w)));
      }
      m0 = gm;
    }
    sd[1][j] = __expf(e0 - m0);
    float offset = m0;

    float ep[8];
#pragma unroll
    for (int k = 0; k < 8; ++k) ep[k] = emb[(size_t)(1 + k) * KK + j];

    auto fwd_body = [&](int t, float e) {
      int p = t & 1, pn = p ^ 1;
      const float4* sv = reinterpret_cast<const float4*>(&sd[p][0]);
      float4 a[16];
#pragma unroll
      for (int k = 0; k < 16; ++k) a[k] = sv[k];
      float sown = sd[p][j];
      float q0 = 0.f, q1 = 0.f, q2 = 0.f, q3 = 0.f;
      float q4 = 0.f, q5 = 0.f, q6 = 0.f, q7 = 0.f;
#pragma unroll
      for (int k = 0; k < 16; k += 8) {
        q0 += a[k].x  * E[4*k]    + a[k].y  * E[4*k+1]
            + a[k].z  * E[4*k+2]  + a[k].w  * E[4*k+3];
        q1 += a[k+1].x* E[4*k+4]  + a[k+1].y* E[4*k+5]
            + a[k+1].z* E[4*k+6]  + a[k+1].w* E[4*k+7];
        q2 += a[k+2].x* E[4*k+8]  + a[k+2].y* E[4*k+9]
            + a[k+2].z* E[4*k+10] + a[k+2].w* E[4*k+11];
        q3 += a[k+3].x* E[4*k+12] + a[k+3].y* E[4*k+13]
            + a[k+3].z* E[4*k+14] + a[k+3].w* E[4*k+15];
        q4 += a[k+4].x* E[4*k+16] + a[k+4].y* E[4*k+17]
            + a[k+4].z* E[4*k+18] + a[k+4].w* E[4*k+19];
        q5 += a[k+5].x* E[4*k+20] + a[k+5].y* E[4*k+21]
            + a[k+5].z* E[4*k+22] + a[k+5].w* E[4*k+23];
        q6 += a[k+6].x* E[4*k+24] + a[k+6].y* E[4*k+25]
            + a[k+6].z* E[4*k+26] + a[k+6].w* E[4*k+27];
        q7 += a[k+7].x* E[4*k+28] + a[k+7].y* E[4*k+29]
            + a[k+7].z* E[4*k+30] + a[k+7].w* E[4*k+31];
      }
      float q = ((q0 + q1) + (q2 + q3)) + ((q4 + q5) + (q6 + q7));
      q *= __expf(e);
      q = mrow[t] ? q : sown;
      if ((t & 7) == 0) {  // renorm from pre-update s (uniform across lanes)
        float gm = -3.4e38f;
#pragma unroll
        for (int k = 0; k < 16; ++k)
          gm = fmaxf(gm, fmaxf(fmaxf(a[k].x, a[k].y), fmaxf(a[k].z, a[k].w)));
        q *= __builtin_amdgcn_rcpf(gm);
        offset += __logf(gm);
      }
      sd[pn][j] = q;
    };

    for (int tb = 1; tb + 7 <= TT - 1; tb += 8) {
#pragma unroll
      for (int k = 0; k < 8; ++k) {
        int t = tb + k;
        float e = ep[k];
        int tpre = t + 8; if (tpre > TT - 1) tpre = TT - 1;
        ep[k] = emb[(size_t)tpre * KK + j];
        fwd_body(t, e);
      }
    }
#pragma unroll
    for (int k = 0; k < 7; ++k) fwd_body(1017 + k, ep[k]);  // t=1017..1023

    float ssum = 0.f;
    {
      const float4* sv = reinterpret_cast<const float4*>(&sd[0][0]);
#pragma unroll
      for (int k = 0; k < 16; ++k) {
        float4 x = sv[k];
        ssum += (x.x + x.y) + (x.z + x.w);
      }
    }
    if (l == 0) atomicAdd(ll_sum, -(offset + __logf(ssum)));
  } else {
    // =========================== VITERBI ===========================
    float C[KK];
#pragma unroll
    for (int r = 0; r < KK; ++r) C[r] = trans[r * KK + j];

    sd[1][j] = emb[j];  // delta0

    float ep[8];
#pragma unroll
    for (int k = 0; k < 8; ++k) ep[k] = emb[(size_t)(1 + k) * KK + j];

    auto vit_body = [&](int t, float e) {
      int p = t & 1, pn = p ^ 1;
      const float4* dv = reinterpret_cast<const float4*>(&sd[p][0]);
      float4 a[16];
#pragma unroll
      for (int k = 0; k < 16; ++k) a[k] = dv[k];
      float down = sd[p][j];
      // per-quarter: add + exact max tree + descending equality scan
      // (first-occurrence argmax, matches numpy; validated absmax=0 in R5)
      float bq[4]; int iq[4];
#pragma unroll
      for (int qd = 0; qd < 4; ++qd) {
        float v16[16];
#pragma unroll
        for (int k = 0; k < 4; ++k) {
          float4 x = a[4*qd + k];
          v16[4*k]   = x.x + C[16*qd + 4*k];
          v16[4*k+1] = x.y + C[16*qd + 4*k+1];
          v16[4*k+2] = x.z + C[16*qd + 4*k+2];
          v16[4*k+3] = x.w + C[16*qd + 4*k+3];
        }
        float m01 = fmaxf(v16[0], v16[1]);
        float m23 = fmaxf(v16[2], v16[3]);
        float m45 = fmaxf(v16[4], v16[5]);
        float m67 = fmaxf(v16[6], v16[7]);
        float m89 = fmaxf(v16[8], v16[9]);
        float mab = fmaxf(v16[10], v16[11]);
        float mcd = fmaxf(v16[12], v16[13]);
        float mef = fmaxf(v16[14], v16[15]);
        float mm = fmaxf(fmaxf(fmaxf(m01, m23), fmaxf(m45, m67)),
                         fmaxf(fmaxf(m89, mab), fmaxf(mcd, mef)));
        int ii = 15;
#pragma unroll
        for (int r = 14; r >= 0; --r) ii = (v16[r] == mm) ? r : ii;
        bq[qd] = mm; iq[qd] = 16*qd + ii;
      }
      float best = fmaxf(fmaxf(bq[0], bq[1]), fmaxf(bq[2], bq[3]));
      int bidx = iq[3];
      bidx = (bq[2] == best) ? iq[2] : bidx;
      bidx = (bq[1] == best) ? iq[1] : bidx;
      bidx = (bq[0] == best) ? iq[0] : bidx;
      int m = mrow[t];
      float nd = m ? (best + e) : down;
      int bp = m ? bidx : j;
      sd[pn][j] = nd;
      bpl[t][j] = (unsigned char)bp;
    };

    for (int tb = 1; tb + 7 <= TT - 1; tb += 8) {
#pragma unroll
      for (int k = 0; k < 8; ++k) {
        int t = tb + k;
        float e = ep[k];
        int tpre = t + 8; if (tpre > TT - 1) tpre = TT - 1;
        ep[k] = emb[(size_t)tpre * KK + j];
        vit_body(t, e);
      }
    }
#pragma unroll
    for (int k = 0; k < 7; ++k) vit_body(1017 + k, ep[k]);  // t=1017..1023

    // ---------------- in-wave epilogue (no barriers) ----------------
    // compose 32-step maps: lane l composes chains (s, j0=l), 32 per lane
    {
      int xs[32];
#pragma unroll
      for (int s = 0; s < 32; ++s) xs[s] = l;
      for (int q = 0; q < 32; ++q) {
#pragma unroll
        for (int s = 0; s < 31; ++s) xs[s] = bpl[32*s + 32 - q][xs[s]];
        if (q < 31) xs[31] = bpl[1023 - q][xs[31]];
      }
#pragma unroll
      for (int s = 0; s < 32; ++s) segm[s][l] = (unsigned char)xs[s];
    }

    // last_tag: butterfly argmax over delta (parity 0), first-max tie-break
    {
      float best = sd[0][j];
      int bidx = j;
#pragma unroll
      for (int off = 1; off <= 32; off <<= 1) {
        float ob = __shfl_xor(best, off);
        int oi = __shfl_xor(bidx, off);
        bool take = (ob > best) || ((ob == best) && (oi < bidx));
        best = take ? ob : best;
        bidx = take ? oi : bidx;
      }
      if (l == 0) {  // boundary walk through segment maps
        unsigned char x = (unsigned char)bidx;
        bs[32] = x;
        for (int s = 31; s >= 0; --s) { x = segm[s][x]; bs[s] = x; }
      }
    }

    // per-segment backtrace: lanes 0..31, segment s = l
    int cnt = 0;
    if (l < 32) {
      int s = l;
      int x = bs[s + 1];
      int tEnd = (s == 31) ? (TT - 1) : (32 * s + 32);
      if (s == 31) {
        int m = mrow[TT - 1];
        out_dec[(size_t)b * TT + TT - 1] = (float)(m ? x : 0);
        cnt += (m && x == tgb[TT - 1]);
      }
      for (int t = tEnd; t >= 32 * s + 1; --t) {
        x = bpl[t][x];
        int m2 = mrow[t - 1];
        out_dec[(size_t)b * TT + t - 1] = (float)(m2 ? x : 0);
        cnt += (m2 && x == tgb[t - 1]);
      }
    }
#pragma unroll
    for (int off = 1; off <= 32; off <<= 1) cnt += __shfl_xor(cnt, off);
    if (l == 0) atomicAdd(match, cnt);
  }
}

__global__ void finalize_kernel(const float* ll_sum, const int* match,
                                const int* maskSum, float* d_out) {
  d_out[0] = -(*ll_sum) / (float)BB;
  d_out[1 + BB * TT] = (float)(*match) / (float)(*maskSum);
}

extern "C" void kernel_launch(void* const* d_in, const int* in_sizes, int n_in,
                              void* d_out, int out_size, void* d_ws, size_t ws_size,
                              hipStream_t stream) {
  const float* em = (const float*)d_in[0];
  const int* tags = (const int*)d_in[1];
  const int* mask = (const int*)d_in[2];       // bool -> int32 on device
  const float* trans = (const float*)d_in[3];
  float* out = (float*)d_out;

  float* ll_sum = (float*)d_ws;
  int* match = (int*)((char*)d_ws + 4);
  int* maskSum = (int*)((char*)d_ws + 8);

  hipMemsetAsync(d_ws, 0, 12, stream);
  crf_mega_kernel<<<2 * BB, 128, 0, stream>>>(em, mask, trans, tags, out + 1,
                                              ll_sum, match, maskSum);
  finalize_kernel<<<1, 1, 0, stream>>>(ll_sum, match, maskSum, out);
}